// Round 13
// baseline (717.156 us; speedup 1.0000x reference)
//
#include <hip/hip_runtime.h>

#define NTOK 16384
#define DMODEL 1024
#define DHID 4096
#define NEXP 8
#define CAP 512

typedef __attribute__((ext_vector_type(8))) short bfrag_t;
typedef __attribute__((ext_vector_type(4))) float ffrag_t;
typedef __attribute__((ext_vector_type(4))) unsigned int u32x4;

__device__ __forceinline__ unsigned short f2bf(float f) {
  unsigned u = __float_as_uint(f);
  u += 0x7FFFu + ((u >> 16) & 1u);
  return (unsigned short)(u >> 16);
}

// gelu(x) = x * sigmoid(x*(1.5957691 + 0.071354814 x^2))  (exact tanh-form identity)
__device__ __forceinline__ float gelu_fast(float x) {
  float t = x * x;
  float z = x * fmaf(0.071354814f, t, 1.5957691f);
  float e = __expf(-z);
  return x * __builtin_amdgcn_rcpf(1.0f + e);
}

// ================== k_prep: 18 weight transposes + router, ONE launch ==================
// blocks 0..18431: transpose (1024 blocks per matrix; z<9 w1-group 64x16, z>=9 w2-group 16x64)
// blocks 18432..22527: router (4 tokens per block) + fused x->bf16
__global__ __launch_bounds__(256) void k_prep(
    const float* __restrict__ sw1, const float* __restrict__ ew1,
    const float* __restrict__ sw2, const float* __restrict__ ew2,
    unsigned short* __restrict__ w1t, unsigned short* __restrict__ ew1t,
    unsigned short* __restrict__ w2t, unsigned short* __restrict__ ew2t,
    const float* __restrict__ x, const float* __restrict__ gw,
    const float* __restrict__ gb, const float* __restrict__ temp,
    float* __restrict__ probs, unsigned short* __restrict__ xb) {
  __shared__ char smem[32768];
  const int id = blockIdx.x;
  if (id < 18432) {
    float(*tile)[65] = (float(*)[65])smem;
    const int zb = id >> 10, r = id & 1023;
    const float* in;
    unsigned short* out;
    int K, N, bx, by;
    if (zb < 9) {
      K = DMODEL; N = DHID;
      bx = r & 63; by = r >> 6;
      if (zb == 0) { in = sw1; out = w1t; }
      else { in = ew1 + (size_t)(zb - 1) * K * N; out = ew1t + (size_t)(zb - 1) * N * K; }
    } else {
      K = DHID; N = DMODEL;
      bx = r & 15; by = r >> 4;
      if (zb == 9) { in = sw2; out = w2t; }
      else { in = ew2 + (size_t)(zb - 10) * K * N; out = ew2t + (size_t)(zb - 10) * N * K; }
    }
    const int n0 = bx * 64, k0 = by * 64;
    const int tx = threadIdx.x & 63, ty = threadIdx.x >> 6;
#pragma unroll
    for (int i = 0; i < 16; ++i) {
      const int k = ty * 16 + i;
      tile[k][tx] = in[(size_t)(k0 + k) * N + n0 + tx];
    }
    __syncthreads();
    const int sx = threadIdx.x & 7, sy = threadIdx.x >> 3;
#pragma unroll
    for (int j = 0; j < 2; ++j) {
      const int n = sy + j * 32;
      u32x4 v;
      v.x = (unsigned)f2bf(tile[sx * 8 + 0][n]) | ((unsigned)f2bf(tile[sx * 8 + 1][n]) << 16);
      v.y = (unsigned)f2bf(tile[sx * 8 + 2][n]) | ((unsigned)f2bf(tile[sx * 8 + 3][n]) << 16);
      v.z = (unsigned)f2bf(tile[sx * 8 + 4][n]) | ((unsigned)f2bf(tile[sx * 8 + 5][n]) << 16);
      v.w = (unsigned)f2bf(tile[sx * 8 + 6][n]) | ((unsigned)f2bf(tile[sx * 8 + 7][n]) << 16);
      *(u32x4*)&out[(size_t)(n0 + n) * K + k0 + sx * 8] = v;
    }
  } else {
    float* gws = (float*)smem;
    const int rb = id - 18432;
    for (int i = threadIdx.x; i < DMODEL * NEXP; i += 256) gws[i] = gw[i];
    __syncthreads();
    const int wave = threadIdx.x >> 6, lane = threadIdx.x & 63;
    const int t = rb * 4 + wave;
    const float* xr = x + (size_t)t * DMODEL;
    unsigned short* xw = xb + (size_t)t * DMODEL;
    float acc[NEXP];
#pragma unroll
    for (int e = 0; e < NEXP; ++e) acc[e] = 0.f;
    for (int d = lane; d < DMODEL; d += 64) {
      float xv = xr[d];
      xw[d] = f2bf(xv);
#pragma unroll
      for (int e = 0; e < NEXP; ++e) acc[e] += xv * gws[d * NEXP + e];
    }
#pragma unroll
    for (int off = 32; off >= 1; off >>= 1) {
#pragma unroll
      for (int e = 0; e < NEXP; ++e) acc[e] += __shfl_xor(acc[e], off);
    }
    if (lane == 0) {
      float st = fmaxf(temp[0], 0.1f);
      float m = -1e30f;
#pragma unroll
      for (int e = 0; e < NEXP; ++e) { acc[e] = (acc[e] + gb[e]) / st; m = fmaxf(m, acc[e]); }
      float s = 0.f;
#pragma unroll
      for (int e = 0; e < NEXP; ++e) { acc[e] = expf(acc[e] - m); s += acc[e]; }
      float inv = 1.f / s;
#pragma unroll
      for (int e = 0; e < NEXP; ++e) probs[(size_t)e * NTOK + t] = acc[e] * inv;
    }
  }
}

// ------- exact top-512 per expert (radix select, tie -> lowest index) + slot map -------
__global__ __launch_bounds__(1024) void k_topk(const float* __restrict__ probs, int* __restrict__ tok,
                                               float* __restrict__ scores, int* __restrict__ eqbuf,
                                               int* __restrict__ slot) {
  const int e = blockIdx.x;
  const float* p = probs + (size_t)e * NTOK;
  int* eq = eqbuf + (size_t)e * NTOK;
  int* sl = slot + (size_t)e * NTOK;
  __shared__ int hist[256];
  __shared__ unsigned sh_pref;
  __shared__ int sh_k, sh_gt, sh_eq, sh_cnt;
  const int tid = threadIdx.x;
  const int NTHR = 1024;
  for (int t = tid; t < NTOK; t += NTHR) sl[t] = -1;
  if (tid == 0) { sh_pref = 0u; sh_k = CAP; }
  __syncthreads();
  for (int pass = 3; pass >= 0; --pass) {
    if (tid < 256) hist[tid] = 0;
    __syncthreads();
    const unsigned pref = sh_pref;
    const int shift = pass * 8;
    for (int t = tid; t < NTOK; t += NTHR) {
      unsigned key = __float_as_uint(p[t]);
      bool cand = (pass == 3) || ((key >> (shift + 8)) == pref);
      if (cand) atomicAdd(&hist[(key >> shift) & 255], 1);
    }
    __syncthreads();
    if (tid == 0) {
      int k = sh_k;
      int d = 255;
      while (hist[d] < k) { k -= hist[d]; --d; }
      sh_k = k;
      sh_pref = (pref << 8) | (unsigned)d;
    }
    __syncthreads();
  }
  const unsigned Kstar = sh_pref;
  const int need_eq = sh_k;
  if (tid == 0) { sh_gt = 0; sh_eq = 0; }
  __syncthreads();
  for (int t = tid; t < NTOK; t += NTHR) {
    unsigned key = __float_as_uint(p[t]);
    if (key > Kstar) {
      int pos = atomicAdd(&sh_gt, 1);
      tok[e * CAP + pos] = t;
      scores[e * CAP + pos] = p[t];
      sl[t] = pos;
    } else if (key == Kstar) {
      int q = atomicAdd(&sh_eq, 1);
      eq[q] = t;
    }
  }
  __syncthreads();
  const int cg = sh_gt, ce = sh_eq;
  if (ce <= need_eq) {
    for (int j = tid; j < ce; j += NTHR) {
      tok[e * CAP + cg + j] = eq[j];
      scores[e * CAP + cg + j] = p[eq[j]];
      sl[eq[j]] = cg + j;
    }
  } else {
    int lo = 0, hi = NTOK - 1;
    while (lo < hi) {
      int mid = (lo + hi) >> 1;
      if (tid == 0) sh_cnt = 0;
      __syncthreads();
      for (int j = tid; j < ce; j += NTHR)
        if (eq[j] <= mid) atomicAdd(&sh_cnt, 1);
      __syncthreads();
      if (sh_cnt >= need_eq) hi = mid; else lo = mid + 1;
      __syncthreads();
    }
    if (tid == 0) sh_cnt = 0;
    __syncthreads();
    for (int j = tid; j < ce; j += NTHR) {
      if (eq[j] <= lo) {
        int pos = cg + atomicAdd(&sh_cnt, 1);
        tok[e * CAP + pos] = eq[j];
        scores[e * CAP + pos] = p[eq[j]];
        sl[eq[j]] = pos;
      }
    }
  }
}

// ================== k_gemm1: shared FFN-1 + expert FFN-1(gather), ONE launch ==================
// blocks 0..4095: shared (slab XCD swizzle over 128x32); 4096..5119: expert e=(id-4096)>>7,
// 4x32 tile grid, A rows gathered via tok. Both: K=DMODEL, N-tile=128, gelu->bf16 bounce.
__global__ __launch_bounds__(256, 4) void k_gemm1(
    const unsigned short* __restrict__ xb,
    const unsigned short* __restrict__ w1t, const unsigned short* __restrict__ ew1t,
    const float* __restrict__ sb1, const float* __restrict__ eb1,
    unsigned short* __restrict__ hs, unsigned short* __restrict__ he,
    const int* __restrict__ tok) {
  const int id = blockIdx.x;
  int m0, n0, gmode, tbase = 0;
  const unsigned short* Bt;
  const float* bz;
  unsigned short* outB;
  if (id < 4096) {
    const int x = id & 7, c = id >> 3;  // slab swizzle, gx=128 (H=16), gy=32
    m0 = (x * 16 + (c & 15)) * 128;
    n0 = (c >> 4) * 128;
    Bt = w1t; bz = sb1; outB = hs; gmode = 0;
  } else {
    const int rid = id - 4096;
    const int e = rid >> 7, r = rid & 127;  // 4 x 32 per expert
    m0 = (r & 3) * 128;
    n0 = (r >> 2) * 128;
    Bt = ew1t + (size_t)e * (DHID * DMODEL);
    bz = eb1 + (size_t)e * DHID;
    outB = he + (size_t)e * (CAP * DHID);
    gmode = 1;
    tbase = e * CAP;
  }
  const int tid = threadIdx.x, wave = tid >> 6, lane = tid & 63;
  const int wm = (wave >> 1) * 64, wn = (wave & 1) * 64;

  __shared__ alignas(16) unsigned short sh[128 * 128];
  unsigned short* As = sh;
  unsigned short* Bs = sh + 128 * 64;

  ffrag_t acc[4][4];
#pragma unroll
  for (int i = 0; i < 4; ++i)
#pragma unroll
    for (int j = 0; j < 4; ++j)
#pragma unroll
      for (int r = 0; r < 4; ++r) acc[i][j][r] = 0.f;

  int lb[4];
  const unsigned short* rowA[4];
  const unsigned short* rowB[4];
#pragma unroll
  for (int it = 0; it < 4; ++it) {
    int L = it * 256 + tid;
    int rr = L >> 3;
    int gg = (L & 7) ^ (rr & 7);
    lb[it] = (it * 256 + wave * 64) * 16;
    const int arow = gmode ? tok[tbase + m0 + rr] : (m0 + rr);
    rowA[it] = xb + (size_t)arow * DMODEL + gg * 8;
    rowB[it] = Bt + (size_t)(n0 + rr) * DMODEL + gg * 8;
  }

  for (int kt = 0; kt < DMODEL; kt += 64) {
#pragma unroll
    for (int it = 0; it < 4; ++it) {
      __builtin_amdgcn_global_load_lds(
          (const __attribute__((address_space(1))) unsigned int*)(rowA[it] + kt),
          (__attribute__((address_space(3))) unsigned int*)((char*)As + lb[it]), 16, 0, 0);
      __builtin_amdgcn_global_load_lds(
          (const __attribute__((address_space(1))) unsigned int*)(rowB[it] + kt),
          (__attribute__((address_space(3))) unsigned int*)((char*)Bs + lb[it]), 16, 0, 0);
    }
    __syncthreads();
#pragma unroll
    for (int kk = 0; kk < 2; ++kk) {
      bfrag_t af[4], bf[4];
      const int gl = kk * 4 + (lane >> 4);
#pragma unroll
      for (int mi = 0; mi < 4; ++mi) {
        int r = wm + mi * 16 + (lane & 15);
        af[mi] = *(const bfrag_t*)&As[r * 64 + ((gl ^ (r & 7)) * 8)];
      }
#pragma unroll
      for (int ni = 0; ni < 4; ++ni) {
        int r = wn + ni * 16 + (lane & 15);
        bf[ni] = *(const bfrag_t*)&Bs[r * 64 + ((gl ^ (r & 7)) * 8)];
      }
#pragma unroll
      for (int mi = 0; mi < 4; ++mi)
#pragma unroll
        for (int ni = 0; ni < 4; ++ni)
          acc[mi][ni] = __builtin_amdgcn_mfma_f32_16x16x32_bf16(af[mi], bf[ni], acc[mi][ni], 0, 0, 0);
    }
    __syncthreads();
  }

  const int rsub = (lane >> 4) * 4, cs = lane & 15;
  float bv[4];
#pragma unroll
  for (int ni = 0; ni < 4; ++ni) bv[ni] = bz[n0 + wn + ni * 16 + cs];
#pragma unroll
  for (int mi = 0; mi < 4; ++mi)
#pragma unroll
    for (int ni = 0; ni < 4; ++ni)
#pragma unroll
      for (int r = 0; r < 4; ++r) {
        float v = acc[mi][ni][r] + bv[ni];
        sh[(wm + mi * 16 + rsub + r) * 128 + (wn + ni * 16 + cs)] = f2bf(gelu_fast(v));
      }
  __syncthreads();
  const int seg = tid & 15, rw = tid >> 4;
#pragma unroll
  for (int rep = 0; rep < 8; ++rep) {
    const int row = rep * 16 + rw;
    u32x4 v = *(const u32x4*)&sh[row * 128 + seg * 8];
    *(u32x4*)&outB[(size_t)(m0 + row) * DHID + n0 + seg * 8] = v;
  }
}

// =====================================================================================
// m97-structure GEMM (MODE 3 / MODE 4 only now):
// MODE 3: dense score-scaled f32 partial store to outF[(zb*ksplit+kc)*M+m][n] (no atomics)
// MODE 4: shared output + fused routed combine from pe via slot map, nt stores.
//   MODE 4 reuses params: tok -> slot[NEXP][NTOK], scale -> pe[(e*2+kc)][CAP][DMODEL].
// =====================================================================================
template <int MODE, bool GATHER, bool NT>
__global__ __launch_bounds__(256, 4) void k_gemm(
    const unsigned short* __restrict__ A, const unsigned short* __restrict__ Bt,
    const float* __restrict__ bias, float* __restrict__ outF, unsigned short* __restrict__ outB,
    const int* __restrict__ tok, const float* __restrict__ scale,
    int M, int N, int Kloop, int LDK, int ksplit) {
  const int zb = blockIdx.z / ksplit;
  const int kc = blockIdx.z % ksplit;
  if (!GATHER) A += (size_t)zb * M * LDK;
  A += (size_t)kc * Kloop;
  Bt += (size_t)zb * N * LDK + (size_t)kc * Kloop;
  const float* bz = bias + (size_t)zb * N;

  const int gx = gridDim.x, gy = gridDim.y;
  const int nwg = gx * gy;
  const int id = blockIdx.x + blockIdx.y * gx;
  int bx, by;
  if ((gx & 7) == 0) {
    const int x = id & 7, c = id >> 3, H = gx >> 3;
    bx = x * H + (c % H);
    by = c / H;
  } else if ((nwg & 7) == 0) {
    const int q = nwg >> 3;
    const int sw = (id & 7) * q + (id >> 3);
    bx = sw % gx;
    by = sw / gx;
  } else {
    bx = blockIdx.x;
    by = blockIdx.y;
  }
  const int m0 = bx * 128, n0 = by * 128;

  const int tid = threadIdx.x, wave = tid >> 6, lane = tid & 63;
  const int wm = (wave >> 1) * 64, wn = (wave & 1) * 64;

  __shared__ alignas(16) unsigned short sh[128 * 128];
  unsigned short* As = sh;
  unsigned short* Bs = sh + 128 * 64;

  ffrag_t acc[4][4];
#pragma unroll
  for (int i = 0; i < 4; ++i)
#pragma unroll
    for (int j = 0; j < 4; ++j)
#pragma unroll
      for (int r = 0; r < 4; ++r) acc[i][j][r] = 0.f;

  int lb[4];
  const unsigned short* rowA[4];
  const unsigned short* rowB[4];
#pragma unroll
  for (int it = 0; it < 4; ++it) {
    int L = it * 256 + tid;
    int rr = L >> 3;
    int gg = (L & 7) ^ (rr & 7);
    lb[it] = (it * 256 + wave * 64) * 16;
    const unsigned short* ab =
        GATHER ? (A + (size_t)tok[zb * M + m0 + rr] * LDK) : (A + (size_t)(m0 + rr) * LDK);
    rowA[it] = ab + gg * 8;
    rowB[it] = Bt + (size_t)(n0 + rr) * LDK + gg * 8;
  }

  for (int kt = 0; kt < Kloop; kt += 64) {
#pragma unroll
    for (int it = 0; it < 4; ++it) {
      __builtin_amdgcn_global_load_lds(
          (const __attribute__((address_space(1))) unsigned int*)(rowA[it] + kt),
          (__attribute__((address_space(3))) unsigned int*)((char*)As + lb[it]), 16, 0, 0);
      __builtin_amdgcn_global_load_lds(
          (const __attribute__((address_space(1))) unsigned int*)(rowB[it] + kt),
          (__attribute__((address_space(3))) unsigned int*)((char*)Bs + lb[it]), 16, 0, 0);
    }
    __syncthreads();
#pragma unroll
    for (int kk = 0; kk < 2; ++kk) {
      bfrag_t af[4], bf[4];
      const int gl = kk * 4 + (lane >> 4);
#pragma unroll
      for (int mi = 0; mi < 4; ++mi) {
        int r = wm + mi * 16 + (lane & 15);
        af[mi] = *(const bfrag_t*)&As[r * 64 + ((gl ^ (r & 7)) * 8)];
      }
#pragma unroll
      for (int ni = 0; ni < 4; ++ni) {
        int r = wn + ni * 16 + (lane & 15);
        bf[ni] = *(const bfrag_t*)&Bs[r * 64 + ((gl ^ (r & 7)) * 8)];
      }
#pragma unroll
      for (int mi = 0; mi < 4; ++mi)
#pragma unroll
        for (int ni = 0; ni < 4; ++ni)
          acc[mi][ni] = __builtin_amdgcn_mfma_f32_16x16x32_bf16(af[mi], bf[ni], acc[mi][ni], 0, 0, 0);
    }
    __syncthreads();
  }

  const int rsub = (lane >> 4) * 4, cs = lane & 15;
  if (MODE == 3) {  // dense score-scaled partial store (cached)
    float* po = outF + (size_t)blockIdx.z * M * N;
#pragma unroll
    for (int ni = 0; ni < 4; ++ni) {
      const int n = n0 + wn + ni * 16 + cs;
      const float bv = (kc == 0) ? bz[n] : 0.f;
#pragma unroll
      for (int mi = 0; mi < 4; ++mi)
#pragma unroll
        for (int r = 0; r < 4; ++r) {
          const int m = m0 + wm + mi * 16 + rsub + r;
          const float s = scale[zb * M + m];
          po[(size_t)m * N + n] = (acc[mi][ni][r] + bv) * s;
        }
    }
  } else {  // MODE 4: shared + fused routed combine, nt stores
    const int* slot = tok;
    const float* pe = scale;
    float bv[4];
#pragma unroll
    for (int ni = 0; ni < 4; ++ni) bv[ni] = bz[n0 + wn + ni * 16 + cs];
#pragma unroll
    for (int mi = 0; mi < 4; ++mi) {
#pragma unroll
      for (int r = 0; r < 4; ++r) {
        const int m = m0 + wm + mi * 16 + rsub + r;
        float ex[4] = {0.f, 0.f, 0.f, 0.f};
#pragma unroll
        for (int e = 0; e < NEXP; ++e) {
          const int sl = slot[(size_t)e * NTOK + m];
          if (sl >= 0) {
            const float* p0 = pe + ((size_t)(e * 2 + 0) * CAP + sl) * DMODEL;
            const float* p1 = pe + ((size_t)(e * 2 + 1) * CAP + sl) * DMODEL;
#pragma unroll
            for (int ni = 0; ni < 4; ++ni) {
              const int n = n0 + wn + ni * 16 + cs;
              ex[ni] += p0[n] + p1[n];
            }
          }
        }
#pragma unroll
        for (int ni = 0; ni < 4; ++ni) {
          const int n = n0 + wn + ni * 16 + cs;
          __builtin_nontemporal_store(acc[mi][ni][r] + bv[ni] + ex[ni],
                                      &outF[(size_t)m * N + n]);
        }
      }
    }
  }
}

extern "C" void kernel_launch(void* const* d_in, const int* in_sizes, int n_in,
                              void* d_out, int out_size, void* d_ws, size_t ws_size,
                              hipStream_t stream) {
  const float* x      = (const float*)d_in[0];
  const float* gate_w = (const float*)d_in[1];
  const float* gate_b = (const float*)d_in[2];
  const float* temp   = (const float*)d_in[3];
  const float* sw1    = (const float*)d_in[4];
  const float* sb1    = (const float*)d_in[5];
  const float* sw2    = (const float*)d_in[6];
  const float* sb2    = (const float*)d_in[7];
  const float* ew1    = (const float*)d_in[8];
  const float* eb1    = (const float*)d_in[9];
  const float* ew2    = (const float*)d_in[10];
  const float* eb2    = (const float*)d_in[11];
  float* out = (float*)d_out;

  char* ws = (char*)d_ws;
  size_t o = 0;
  auto take = [&](size_t bytes) { char* p = ws + o; o += (bytes + 255) & ~(size_t)255; return p; };
  unsigned short* x_bf = (unsigned short*)take((size_t)NTOK * DMODEL * 2);
  unsigned short* w1t  = (unsigned short*)take((size_t)DMODEL * DHID * 2);
  unsigned short* w2t  = (unsigned short*)take((size_t)DHID * DMODEL * 2);
  unsigned short* ew1t = (unsigned short*)take((size_t)NEXP * DMODEL * DHID * 2);
  unsigned short* ew2t = (unsigned short*)take((size_t)NEXP * DHID * DMODEL * 2);
  float* probs         = (float*)take((size_t)NEXP * NTOK * 4);
  int* tok             = (int*)take((size_t)NEXP * CAP * 4);
  float* scores        = (float*)take((size_t)NEXP * CAP * 4);
  int* eqbuf           = (int*)take((size_t)NEXP * NTOK * 4);
  int* slot            = (int*)take((size_t)NEXP * NTOK * 4);
  float* pe            = (float*)take((size_t)NEXP * 2 * CAP * DMODEL * 4);
  unsigned short* he   = (unsigned short*)take((size_t)NEXP * CAP * DHID * 2);
  unsigned short* hs   = (unsigned short*)take((size_t)NTOK * DHID * 2);

  // 1: all 18 weight transposes + router + x->bf16 in ONE launch
  k_prep<<<18432 + 4096, 256, 0, stream>>>(sw1, ew1, sw2, ew2, w1t, ew1t, w2t, ew2t,
                                           x, gate_w, gate_b, temp, probs, x_bf);

  // 2: top-k (+ slot map)
  k_topk<<<NEXP, 1024, 0, stream>>>(probs, tok, scores, eqbuf, slot);

  // 3: shared FFN-1 + expert FFN-1 (fused gather) in ONE launch
  k_gemm1<<<4096 + NEXP * 128, 256, 0, stream>>>(x_bf, w1t, ew1t, sb1, eb1, hs, he, tok);

  // 4: expert FFN-2 dense scaled partials (no atomics)
  k_gemm<3, false, false><<<dim3(4, 8, NEXP * 2), 256, 0, stream>>>(
      he, ew2t, eb2, pe, nullptr, nullptr, scores, CAP, DMODEL, DHID / 2, DHID, 2);

  // 5: shared FFN-2 with fused routed combine (reads pe via slot map), nt out stores
  k_gemm<4, false, true><<<dim3(128, 8, 1), 256, 0, stream>>>(
      hs, w2t, sb2, out, nullptr, slot, pe, NTOK, DMODEL, DHID, DHID, 1);
}

// Round 14
// 606.564 us; speedup vs baseline: 1.1823x; 1.1823x over previous
//
#include <hip/hip_runtime.h>

#define NTOK 16384
#define DMODEL 1024
#define DHID 4096
#define NEXP 8
#define CAP 512

typedef __attribute__((ext_vector_type(8))) short bfrag_t;
typedef __attribute__((ext_vector_type(4))) float ffrag_t;
typedef __attribute__((ext_vector_type(4))) unsigned int u32x4;

__device__ __forceinline__ unsigned short f2bf(float f) {
  unsigned u = __float_as_uint(f);
  u += 0x7FFFu + ((u >> 16) & 1u);
  return (unsigned short)(u >> 16);
}

// gelu(x) = x * sigmoid(x*(1.5957691 + 0.071354814 x^2))  (exact tanh-form identity)
__device__ __forceinline__ float gelu_fast(float x) {
  float t = x * x;
  float z = x * fmaf(0.071354814f, t, 1.5957691f);
  float e = __expf(-z);
  return x * __builtin_amdgcn_rcpf(1.0f + e);
}

// ================== k_prep: 18 weight transposes + router, ONE launch ==================
// (safe merge: both halves are pure streaming, no intra-dispatch cache reuse to disturb)
__global__ __launch_bounds__(256) void k_prep(
    const float* __restrict__ sw1, const float* __restrict__ ew1,
    const float* __restrict__ sw2, const float* __restrict__ ew2,
    unsigned short* __restrict__ w1t, unsigned short* __restrict__ ew1t,
    unsigned short* __restrict__ w2t, unsigned short* __restrict__ ew2t,
    const float* __restrict__ x, const float* __restrict__ gw,
    const float* __restrict__ gb, const float* __restrict__ temp,
    float* __restrict__ probs, unsigned short* __restrict__ xb) {
  __shared__ char smem[32768];
  const int id = blockIdx.x;
  if (id < 18432) {
    float(*tile)[65] = (float(*)[65])smem;
    const int zb = id >> 10, r = id & 1023;
    const float* in;
    unsigned short* out;
    int K, N, bx, by;
    if (zb < 9) {
      K = DMODEL; N = DHID;
      bx = r & 63; by = r >> 6;
      if (zb == 0) { in = sw1; out = w1t; }
      else { in = ew1 + (size_t)(zb - 1) * K * N; out = ew1t + (size_t)(zb - 1) * N * K; }
    } else {
      K = DHID; N = DMODEL;
      bx = r & 15; by = r >> 4;
      if (zb == 9) { in = sw2; out = w2t; }
      else { in = ew2 + (size_t)(zb - 10) * K * N; out = ew2t + (size_t)(zb - 10) * N * K; }
    }
    const int n0 = bx * 64, k0 = by * 64;
    const int tx = threadIdx.x & 63, ty = threadIdx.x >> 6;
#pragma unroll
    for (int i = 0; i < 16; ++i) {
      const int k = ty * 16 + i;
      tile[k][tx] = in[(size_t)(k0 + k) * N + n0 + tx];
    }
    __syncthreads();
    const int sx = threadIdx.x & 7, sy = threadIdx.x >> 3;
#pragma unroll
    for (int j = 0; j < 2; ++j) {
      const int n = sy + j * 32;
      u32x4 v;
      v.x = (unsigned)f2bf(tile[sx * 8 + 0][n]) | ((unsigned)f2bf(tile[sx * 8 + 1][n]) << 16);
      v.y = (unsigned)f2bf(tile[sx * 8 + 2][n]) | ((unsigned)f2bf(tile[sx * 8 + 3][n]) << 16);
      v.z = (unsigned)f2bf(tile[sx * 8 + 4][n]) | ((unsigned)f2bf(tile[sx * 8 + 5][n]) << 16);
      v.w = (unsigned)f2bf(tile[sx * 8 + 6][n]) | ((unsigned)f2bf(tile[sx * 8 + 7][n]) << 16);
      *(u32x4*)&out[(size_t)(n0 + n) * K + k0 + sx * 8] = v;
    }
  } else {
    float* gws = (float*)smem;
    const int rb = id - 18432;
    for (int i = threadIdx.x; i < DMODEL * NEXP; i += 256) gws[i] = gw[i];
    __syncthreads();
    const int wave = threadIdx.x >> 6, lane = threadIdx.x & 63;
    const int t = rb * 4 + wave;
    const float* xr = x + (size_t)t * DMODEL;
    unsigned short* xw = xb + (size_t)t * DMODEL;
    float acc[NEXP];
#pragma unroll
    for (int e = 0; e < NEXP; ++e) acc[e] = 0.f;
    for (int d = lane; d < DMODEL; d += 64) {
      float xv = xr[d];
      xw[d] = f2bf(xv);
#pragma unroll
      for (int e = 0; e < NEXP; ++e) acc[e] += xv * gws[d * NEXP + e];
    }
#pragma unroll
    for (int off = 32; off >= 1; off >>= 1) {
#pragma unroll
      for (int e = 0; e < NEXP; ++e) acc[e] += __shfl_xor(acc[e], off);
    }
    if (lane == 0) {
      float st = fmaxf(temp[0], 0.1f);
      float m = -1e30f;
#pragma unroll
      for (int e = 0; e < NEXP; ++e) { acc[e] = (acc[e] + gb[e]) / st; m = fmaxf(m, acc[e]); }
      float s = 0.f;
#pragma unroll
      for (int e = 0; e < NEXP; ++e) { acc[e] = expf(acc[e] - m); s += acc[e]; }
      float inv = 1.f / s;
#pragma unroll
      for (int e = 0; e < NEXP; ++e) probs[(size_t)e * NTOK + t] = acc[e] * inv;
    }
  }
}

// ------- exact top-512 per expert (radix select, tie -> lowest index) + slot map -------
__global__ __launch_bounds__(1024) void k_topk(const float* __restrict__ probs, int* __restrict__ tok,
                                               float* __restrict__ scores, int* __restrict__ eqbuf,
                                               int* __restrict__ slot) {
  const int e = blockIdx.x;
  const float* p = probs + (size_t)e * NTOK;
  int* eq = eqbuf + (size_t)e * NTOK;
  int* sl = slot + (size_t)e * NTOK;
  __shared__ int hist[256];
  __shared__ unsigned sh_pref;
  __shared__ int sh_k, sh_gt, sh_eq, sh_cnt;
  const int tid = threadIdx.x;
  const int NTHR = 1024;
  for (int t = tid; t < NTOK; t += NTHR) sl[t] = -1;
  if (tid == 0) { sh_pref = 0u; sh_k = CAP; }
  __syncthreads();
  for (int pass = 3; pass >= 0; --pass) {
    if (tid < 256) hist[tid] = 0;
    __syncthreads();
    const unsigned pref = sh_pref;
    const int shift = pass * 8;
    for (int t = tid; t < NTOK; t += NTHR) {
      unsigned key = __float_as_uint(p[t]);
      bool cand = (pass == 3) || ((key >> (shift + 8)) == pref);
      if (cand) atomicAdd(&hist[(key >> shift) & 255], 1);
    }
    __syncthreads();
    if (tid == 0) {
      int k = sh_k;
      int d = 255;
      while (hist[d] < k) { k -= hist[d]; --d; }
      sh_k = k;
      sh_pref = (pref << 8) | (unsigned)d;
    }
    __syncthreads();
  }
  const unsigned Kstar = sh_pref;
  const int need_eq = sh_k;
  if (tid == 0) { sh_gt = 0; sh_eq = 0; }
  __syncthreads();
  for (int t = tid; t < NTOK; t += NTHR) {
    unsigned key = __float_as_uint(p[t]);
    if (key > Kstar) {
      int pos = atomicAdd(&sh_gt, 1);
      tok[e * CAP + pos] = t;
      scores[e * CAP + pos] = p[t];
      sl[t] = pos;
    } else if (key == Kstar) {
      int q = atomicAdd(&sh_eq, 1);
      eq[q] = t;
    }
  }
  __syncthreads();
  const int cg = sh_gt, ce = sh_eq;
  if (ce <= need_eq) {
    for (int j = tid; j < ce; j += NTHR) {
      tok[e * CAP + cg + j] = eq[j];
      scores[e * CAP + cg + j] = p[eq[j]];
      sl[eq[j]] = cg + j;
    }
  } else {
    int lo = 0, hi = NTOK - 1;
    while (lo < hi) {
      int mid = (lo + hi) >> 1;
      if (tid == 0) sh_cnt = 0;
      __syncthreads();
      for (int j = tid; j < ce; j += NTHR)
        if (eq[j] <= mid) atomicAdd(&sh_cnt, 1);
      __syncthreads();
      if (sh_cnt >= need_eq) hi = mid; else lo = mid + 1;
      __syncthreads();
    }
    if (tid == 0) sh_cnt = 0;
    __syncthreads();
    for (int j = tid; j < ce; j += NTHR) {
      if (eq[j] <= lo) {
        int pos = cg + atomicAdd(&sh_cnt, 1);
        tok[e * CAP + pos] = eq[j];
        scores[e * CAP + pos] = p[eq[j]];
        sl[eq[j]] = pos;
      }
    }
  }
}

// =====================================================================================
// m97-structure GEMM: 128x128, BK=64, 4 waves, single 32KB LDS, 4 blocks/CU.
// GATHER: A rows indirected via tok (fused token gather).
// MODE 0: bf16(gelu) LDS-bounce; MODE 3: dense score-scaled f32 partial store;
// MODE 4: shared output + fused routed combine from pe via slot map, nt stores.
//   MODE 4 reuses params: tok -> slot[NEXP][NTOK], scale -> pe[(e*2+kc)][CAP][DMODEL].
// =====================================================================================
template <int MODE, bool GATHER, bool NT>
__global__ __launch_bounds__(256, 4) void k_gemm(
    const unsigned short* __restrict__ A, const unsigned short* __restrict__ Bt,
    const float* __restrict__ bias, float* __restrict__ outF, unsigned short* __restrict__ outB,
    const int* __restrict__ tok, const float* __restrict__ scale,
    int M, int N, int Kloop, int LDK, int ksplit) {
  const int zb = blockIdx.z / ksplit;
  const int kc = blockIdx.z % ksplit;
  if (!GATHER) A += (size_t)zb * M * LDK;
  A += (size_t)kc * Kloop;
  Bt += (size_t)zb * N * LDK + (size_t)kc * Kloop;
  const float* bz = bias + (size_t)zb * N;

  const int gx = gridDim.x, gy = gridDim.y;
  const int nwg = gx * gy;
  const int id = blockIdx.x + blockIdx.y * gx;
  int bx, by;
  if ((gx & 7) == 0) {
    const int x = id & 7, c = id >> 3, H = gx >> 3;
    bx = x * H + (c % H);
    by = c / H;
  } else if ((nwg & 7) == 0) {
    const int q = nwg >> 3;
    const int sw = (id & 7) * q + (id >> 3);
    bx = sw % gx;
    by = sw / gx;
  } else {
    bx = blockIdx.x;
    by = blockIdx.y;
  }
  const int m0 = bx * 128, n0 = by * 128;

  const int tid = threadIdx.x, wave = tid >> 6, lane = tid & 63;
  const int wm = (wave >> 1) * 64, wn = (wave & 1) * 64;

  __shared__ alignas(16) unsigned short sh[128 * 128];
  unsigned short* As = sh;
  unsigned short* Bs = sh + 128 * 64;

  ffrag_t acc[4][4];
#pragma unroll
  for (int i = 0; i < 4; ++i)
#pragma unroll
    for (int j = 0; j < 4; ++j)
#pragma unroll
      for (int r = 0; r < 4; ++r) acc[i][j][r] = 0.f;

  int lb[4];
  const unsigned short* rowA[4];
  const unsigned short* rowB[4];
#pragma unroll
  for (int it = 0; it < 4; ++it) {
    int L = it * 256 + tid;
    int rr = L >> 3;
    int gg = (L & 7) ^ (rr & 7);
    lb[it] = (it * 256 + wave * 64) * 16;
    const unsigned short* ab =
        GATHER ? (A + (size_t)tok[zb * M + m0 + rr] * LDK) : (A + (size_t)(m0 + rr) * LDK);
    rowA[it] = ab + gg * 8;
    rowB[it] = Bt + (size_t)(n0 + rr) * LDK + gg * 8;
  }

  for (int kt = 0; kt < Kloop; kt += 64) {
#pragma unroll
    for (int it = 0; it < 4; ++it) {
      __builtin_amdgcn_global_load_lds(
          (const __attribute__((address_space(1))) unsigned int*)(rowA[it] + kt),
          (__attribute__((address_space(3))) unsigned int*)((char*)As + lb[it]), 16, 0, 0);
      __builtin_amdgcn_global_load_lds(
          (const __attribute__((address_space(1))) unsigned int*)(rowB[it] + kt),
          (__attribute__((address_space(3))) unsigned int*)((char*)Bs + lb[it]), 16, 0, 0);
    }
    __syncthreads();
#pragma unroll
    for (int kk = 0; kk < 2; ++kk) {
      bfrag_t af[4], bf[4];
      const int gl = kk * 4 + (lane >> 4);
#pragma unroll
      for (int mi = 0; mi < 4; ++mi) {
        int r = wm + mi * 16 + (lane & 15);
        af[mi] = *(const bfrag_t*)&As[r * 64 + ((gl ^ (r & 7)) * 8)];
      }
#pragma unroll
      for (int ni = 0; ni < 4; ++ni) {
        int r = wn + ni * 16 + (lane & 15);
        bf[ni] = *(const bfrag_t*)&Bs[r * 64 + ((gl ^ (r & 7)) * 8)];
      }
#pragma unroll
      for (int mi = 0; mi < 4; ++mi)
#pragma unroll
        for (int ni = 0; ni < 4; ++ni)
          acc[mi][ni] = __builtin_amdgcn_mfma_f32_16x16x32_bf16(af[mi], bf[ni], acc[mi][ni], 0, 0, 0);
    }
    __syncthreads();
  }

  const int rsub = (lane >> 4) * 4, cs = lane & 15;
  if (MODE == 0) {
    float bv[4];
#pragma unroll
    for (int ni = 0; ni < 4; ++ni) bv[ni] = bz[n0 + wn + ni * 16 + cs];
#pragma unroll
    for (int mi = 0; mi < 4; ++mi)
#pragma unroll
      for (int ni = 0; ni < 4; ++ni)
#pragma unroll
        for (int r = 0; r < 4; ++r) {
          float v = acc[mi][ni][r] + bv[ni];
          sh[(wm + mi * 16 + rsub + r) * 128 + (wn + ni * 16 + cs)] = f2bf(gelu_fast(v));
        }
    __syncthreads();
    const int seg = tid & 15, rw = tid >> 4;
#pragma unroll
    for (int rep = 0; rep < 8; ++rep) {
      const int row = rep * 16 + rw;
      u32x4 v = *(const u32x4*)&sh[row * 128 + seg * 8];
      *(u32x4*)&outB[((size_t)zb * M + m0 + row) * N + n0 + seg * 8] = v;
    }
  } else if (MODE == 3) {  // dense score-scaled partial store (cached)
    float* po = outF + (size_t)blockIdx.z * M * N;
#pragma unroll
    for (int ni = 0; ni < 4; ++ni) {
      const int n = n0 + wn + ni * 16 + cs;
      const float bv = (kc == 0) ? bz[n] : 0.f;
#pragma unroll
      for (int mi = 0; mi < 4; ++mi)
#pragma unroll
        for (int r = 0; r < 4; ++r) {
          const int m = m0 + wm + mi * 16 + rsub + r;
          const float s = scale[zb * M + m];
          po[(size_t)m * N + n] = (acc[mi][ni][r] + bv) * s;
        }
    }
  } else {  // MODE 4: shared + fused routed combine, nt stores
    const int* slot = tok;
    const float* pe = scale;
    float bv[4];
#pragma unroll
    for (int ni = 0; ni < 4; ++ni) bv[ni] = bz[n0 + wn + ni * 16 + cs];
#pragma unroll
    for (int mi = 0; mi < 4; ++mi) {
#pragma unroll
      for (int r = 0; r < 4; ++r) {
        const int m = m0 + wm + mi * 16 + rsub + r;
        float ex[4] = {0.f, 0.f, 0.f, 0.f};
#pragma unroll
        for (int e = 0; e < NEXP; ++e) {
          const int sl = slot[(size_t)e * NTOK + m];
          if (sl >= 0) {
            const float* p0 = pe + ((size_t)(e * 2 + 0) * CAP + sl) * DMODEL;
            const float* p1 = pe + ((size_t)(e * 2 + 1) * CAP + sl) * DMODEL;
#pragma unroll
            for (int ni = 0; ni < 4; ++ni) {
              const int n = n0 + wn + ni * 16 + cs;
              ex[ni] += p0[n] + p1[n];
            }
          }
        }
#pragma unroll
        for (int ni = 0; ni < 4; ++ni) {
          const int n = n0 + wn + ni * 16 + cs;
          __builtin_nontemporal_store(acc[mi][ni][r] + bv[ni] + ex[ni],
                                      &outF[(size_t)m * N + n]);
        }
      }
    }
  }
}

extern "C" void kernel_launch(void* const* d_in, const int* in_sizes, int n_in,
                              void* d_out, int out_size, void* d_ws, size_t ws_size,
                              hipStream_t stream) {
  const float* x      = (const float*)d_in[0];
  const float* gate_w = (const float*)d_in[1];
  const float* gate_b = (const float*)d_in[2];
  const float* temp   = (const float*)d_in[3];
  const float* sw1    = (const float*)d_in[4];
  const float* sb1    = (const float*)d_in[5];
  const float* sw2    = (const float*)d_in[6];
  const float* sb2    = (const float*)d_in[7];
  const float* ew1    = (const float*)d_in[8];
  const float* eb1    = (const float*)d_in[9];
  const float* ew2    = (const float*)d_in[10];
  const float* eb2    = (const float*)d_in[11];
  float* out = (float*)d_out;

  char* ws = (char*)d_ws;
  size_t o = 0;
  auto take = [&](size_t bytes) { char* p = ws + o; o += (bytes + 255) & ~(size_t)255; return p; };
  unsigned short* x_bf = (unsigned short*)take((size_t)NTOK * DMODEL * 2);
  unsigned short* w1t  = (unsigned short*)take((size_t)DMODEL * DHID * 2);
  unsigned short* w2t  = (unsigned short*)take((size_t)DHID * DMODEL * 2);
  unsigned short* ew1t = (unsigned short*)take((size_t)NEXP * DMODEL * DHID * 2);
  unsigned short* ew2t = (unsigned short*)take((size_t)NEXP * DHID * DMODEL * 2);
  float* probs         = (float*)take((size_t)NEXP * NTOK * 4);
  int* tok             = (int*)take((size_t)NEXP * CAP * 4);
  float* scores        = (float*)take((size_t)NEXP * CAP * 4);
  int* eqbuf           = (int*)take((size_t)NEXP * NTOK * 4);
  int* slot            = (int*)take((size_t)NEXP * NTOK * 4);
  float* pe            = (float*)take((size_t)NEXP * 2 * CAP * DMODEL * 4);
  unsigned short* he   = (unsigned short*)take((size_t)NEXP * CAP * DHID * 2);
  unsigned short* hs   = (unsigned short*)take((size_t)NTOK * DHID * 2);

  // 1: all 18 weight transposes + router + x->bf16 in ONE launch (safe streaming merge)
  k_prep<<<18432 + 4096, 256, 0, stream>>>(sw1, ew1, sw2, ew2, w1t, ew1t, w2t, ew2t,
                                           x, gate_w, gate_b, temp, probs, x_bf);

  // 2: top-k (+ slot map)
  k_topk<<<NEXP, 1024, 0, stream>>>(probs, tok, scores, eqbuf, slot);

  // 3: shared FFN-1 (separate launch — merge regressed, R13)
  k_gemm<0, false, false><<<dim3(128, 32, 1), 256, 0, stream>>>(
      x_bf, w1t, sb1, nullptr, hs, nullptr, nullptr, NTOK, DHID, DMODEL, DMODEL, 1);

  // 4: expert FFN-1 with fused gather (compact dispatch keeps weight-panel L2 reuse)
  k_gemm<0, true, false><<<dim3(4, 32, NEXP), 256, 0, stream>>>(
      x_bf, ew1t, eb1, nullptr, he, tok, nullptr, CAP, DHID, DMODEL, DMODEL, 1);

  // 5: expert FFN-2 dense scaled partials (no atomics)
  k_gemm<3, false, false><<<dim3(4, 8, NEXP * 2), 256, 0, stream>>>(
      he, ew2t, eb2, pe, nullptr, nullptr, scores, CAP, DMODEL, DHID / 2, DHID, 2);

  // 6: shared FFN-2 with fused routed combine (reads pe via slot map), nt out stores
  k_gemm<4, false, true><<<dim3(128, 8, 1), 256, 0, stream>>>(
      hs, w2t, sb2, out, nullptr, slot, pe, NTOK, DMODEL, DHID, DHID, 1);
}